// Round 13
// baseline (66.455 us; speedup 1.0000x reference)
//
#include <hip/hip_runtime.h>
#include <hip/hip_bf16.h>

#define LSEQ 2048
#define BB   2048
#define TT   7
#define NFLD 17   // SoA fields: [0..6] vn, [7..13] rn, [14] sc, [15] mc, [16] Lr

typedef float f4 __attribute__((ext_vector_type(4)));

// Load 7 floats from a 4B-aligned row as two overlapping dwordx4 loads.
__device__ __forceinline__ void ld7(const float* __restrict__ p, float* e) {
  f4 lo, hi;
  __builtin_memcpy(&lo, p, 16);
  __builtin_memcpy(&hi, p + 3, 16);
  e[0] = lo.x; e[1] = lo.y; e[2] = lo.z; e[3] = lo.w;
  e[4] = hi.y; e[5] = hi.z; e[6] = hi.w;
}

// ---------------------------------------------------------------------------
// Rank-1 chunk decomposition (R8-R12): after a CC-step chunk the composite
// operator P is rank-1 to ~0.1^CC: P = u v^T.
//   forward role:  v <- (v.E) o ee   -> vn (+ gold score / mask count)
//   backward role: r <- E.(ee o r)   -> rn, Lr  (u = P.1)
// logZ telescopes into independent junction terms -> flat combine + reduce.
// R12 post-mortem: buffer ROTATION (e0=e1) copies in-flight load dest regs ->
// forced wait one iter after issue -> ~600cyc stall/step -> 2.0 TB/s.
// This round: modulo-4 STATIC buffer pipeline (unroll 4, no copies), uniform
// trip count with the c==0 boundary step masked via mi=0.
// NOTE: no min-wave launch_bounds (R5/R7: forcing it spills to scratch).
// ---------------------------------------------------------------------------
template<int KCH>
__global__ __launch_bounds__(256)
void crf_chunk_kernel(const float* __restrict__ em,
                      const int*   __restrict__ tags,
                      const int*   __restrict__ qmask,
                      const int*   __restrict__ mask,
                      const float* __restrict__ self_t,
                      const float* __restrict__ other_t,
                      float* __restrict__ recs) {
  constexpr int CC = LSEQ / KCH;
  constexpr int NG = KCH * BB;
  __shared__ float sE[2][49];    // exp(transitions): [0]=self, [1]=other
  __shared__ float sT[2][49];    // raw transitions (gold-path score)
  int tid = threadIdx.x;
  if (tid < 49) {
    float sv = self_t[tid], ov = other_t[tid];
    sE[0][tid] = __expf(sv); sE[1][tid] = __expf(ov);
    sT[0][tid] = sv;         sT[1][tid] = ov;
  }
  __syncthreads();

  int role = tid >> 7;            // wave-uniform: 0 = forward v, 1 = backward r
  int g = blockIdx.x * 128 + (tid & 127);
  int b = g & (BB - 1);
  int c = g >> 11;                // uniform per block

  float Es[49];                   // SGPR-resident via readfirstlane when uniform
  int loadedCont = -1;

  float eb[4][7];                 // static modulo-4 pipeline buffers
  int tb[4], qb[4], mb[4];

  if (role == 0) {
    // ---------------- forward: vn + gold-path score ----------------
    float v[7] = {1.f,1.f,1.f,1.f,1.f,1.f,1.f};
    float sc = 0.0f;
    int   mc = 0;
    int i_base = c * CC;
    int tp, qp;
    if (c == 0) {
      mc = mask[b]; tp = tags[b]; qp = qmask[b];   // step 0 masked below
    } else {
      tp = tags[(size_t)(i_base - 1) * BB + b];
      qp = qmask[(size_t)(i_base - 1) * BB + b];
    }

    auto LDF = [&](int s, int buf) {
      int i = i_base + s;
      int ii = (i < LSEQ) ? i : (LSEQ - 1);        // clamp (tail prefetch)
      size_t base = (size_t)ii * BB + b;
      ld7(em + base * TT, eb[buf]);
      tb[buf] = tags[base]; qb[buf] = qmask[buf ? base : base];
      qb[buf] = qmask[base]; mb[buf] = mask[base];
    };

    LDF(0, 0); LDF(1, 1); LDF(2, 2);

    for (int j = 0; j < CC; j += 4) {
#pragma unroll
      for (int u = 0; u < 4; ++u) {
        LDF(j + u + 3, (u + 3) & 3);               // depth-3 static prefetch
        int s = j + u;
        const float* e = eb[u];
        int tg = tb[u], qm = qb[u], mi = mb[u];
        if (c == 0 && s == 0) mi = 0;              // boundary step = identity

        int cont = (qm != qp) ? 1 : 0;
        int cf = __builtin_amdgcn_readfirstlane(cont);
        bool uni = __all(cont == cf);
        float ee[7];
#pragma unroll
        for (int t = 0; t < 7; ++t) ee[t] = __expf(e[t]);

        float etag = e[0];
#pragma unroll
        for (int t = 1; t < 7; ++t) etag = (tg == t) ? e[t] : etag;
        float ttag = sT[cont][tp * 7 + tg];
        if (mi) { sc += ttag + etag; ++mc; }
        tp = tg; qp = qm;

        float a[7] = {0.f,0.f,0.f,0.f,0.f,0.f,0.f};
        if (uni) {
          if (cf != loadedCont) {
#pragma unroll
            for (int k = 0; k < 49; ++k)
              Es[k] = __int_as_float(
                  __builtin_amdgcn_readfirstlane(__float_as_int(sE[cf][k])));
            loadedCont = cf;
          }
#pragma unroll
          for (int r = 0; r < 7; ++r) {
            float vr = v[r];
#pragma unroll
            for (int t = 0; t < 7; ++t) a[t] = fmaf(vr, Es[r*7+t], a[t]);
          }
        } else {
          loadedCont = -1;
#pragma unroll
          for (int r = 0; r < 7; ++r) {
            float vr = v[r];
#pragma unroll
            for (int t = 0; t < 7; ++t) a[t] = fmaf(vr, sE[cont][r*7+t], a[t]);
          }
        }
#pragma unroll
        for (int t = 0; t < 7; ++t) v[t] = mi ? a[t] * ee[t] : v[t];

        if ((s & 7) == 7) {                        // overflow-guard renorm
          float ssum = v[0]+v[1]+v[2]+v[3]+v[4]+v[5]+v[6];
          float inv = 1.0f / ssum;
#pragma unroll
          for (int t = 0; t < 7; ++t) v[t] *= inv;
        }
      }
    }
    float ssum = v[0]+v[1]+v[2]+v[3]+v[4]+v[5]+v[6];
    float inv = 1.0f / ssum;
#pragma unroll
    for (int t = 0; t < 7; ++t) recs[(size_t)t * NG + g] = v[t] * inv;
    recs[(size_t)14 * NG + g] = sc;
    recs[(size_t)15 * NG + g] = (float)mc;
  } else {
    // ---------------- backward: rn, Lr  (u = P.1) ----------------
    float r[7] = {1.f,1.f,1.f,1.f,1.f,1.f,1.f};
    float Lr = 0.0f;
    int i_hi = c * CC + CC - 1;

    auto LDB = [&](int s, int buf) {
      int i = i_hi - s;
      int ii = (i > 0) ? i : 0;                    // clamp (tail prefetch)
      size_t base = (size_t)ii * BB + b;
      ld7(em + base * TT, eb[buf]);
      qb[buf] = qmask[base]; mb[buf] = mask[base];
    };

    LDB(0, 0); LDB(1, 1); LDB(2, 2);

    for (int j = 0; j < CC; j += 4) {
#pragma unroll
      for (int u = 0; u < 4; ++u) {
        LDB(j + u + 3, (u + 3) & 3);               // depth-3 static prefetch
        int s = j + u;
        const float* e = eb[u];
        int mi = mb[u];
        if (c == 0 && s == CC - 1) mi = 0;         // boundary step = identity
        int q_i   = qb[u];
        int q_im1 = qb[(u + 1) & 3];               // next-consumed buffer = step s+1 (= i-1)

        int cont = (q_i != q_im1) ? 1 : 0;
        int cf = __builtin_amdgcn_readfirstlane(cont);
        bool uni = __all(cont == cf);
        float ee[7];
#pragma unroll
        for (int t = 0; t < 7; ++t) ee[t] = __expf(e[t]);
        float tmp[7];
#pragma unroll
        for (int t = 0; t < 7; ++t) tmp[t] = ee[t] * r[t];

        float a[7] = {0.f,0.f,0.f,0.f,0.f,0.f,0.f};
        if (uni) {
          if (cf != loadedCont) {
#pragma unroll
            for (int k = 0; k < 49; ++k)
              Es[k] = __int_as_float(
                  __builtin_amdgcn_readfirstlane(__float_as_int(sE[cf][k])));
            loadedCont = cf;
          }
#pragma unroll
          for (int t = 0; t < 7; ++t) {
            float tt = tmp[t];
#pragma unroll
            for (int s2 = 0; s2 < 7; ++s2) a[s2] = fmaf(tt, Es[s2*7+t], a[s2]);
          }
        } else {
          loadedCont = -1;
#pragma unroll
          for (int t = 0; t < 7; ++t) {
            float tt = tmp[t];
#pragma unroll
            for (int s2 = 0; s2 < 7; ++s2) a[s2] = fmaf(tt, sE[cont][s2*7+t], a[s2]);
          }
        }
#pragma unroll
        for (int s2 = 0; s2 < 7; ++s2) r[s2] = mi ? a[s2] : r[s2];

        if ((s & 7) == 7) {                        // renorm with log tracking
          float ssum = r[0]+r[1]+r[2]+r[3]+r[4]+r[5]+r[6];
          Lr += logf(ssum);
          float inv = 1.0f / ssum;
#pragma unroll
          for (int t = 0; t < 7; ++t) r[t] *= inv;
        }
      }
    }
    float ssum = r[0]+r[1]+r[2]+r[3]+r[4]+r[5]+r[6];
    Lr += logf(ssum);
    float inv = 1.0f / ssum;
#pragma unroll
    for (int t = 0; t < 7; ++t) recs[(size_t)(7 + t) * NG + g] = r[t] * inv;
    recs[(size_t)16 * NG + g] = Lr;
  }
}

// ---------------------------------------------------------------------------
// Kernel 2: flat-parallel junction terms + per-block tree reduction.
// ---------------------------------------------------------------------------
template<int KCH>
__global__ __launch_bounds__(256)
void crf_junction_kernel(const float* __restrict__ recs,
                         const float* __restrict__ em,
                         const int*   __restrict__ tags,
                         const float* __restrict__ start_t,
                         const float* __restrict__ end_t,
                         float* __restrict__ partials) {
  constexpr int NG = KCH * BB;
  int tid = threadIdx.x;
  int g = blockIdx.x * 256 + tid;
  int b = g & (BB - 1);
  int c = g >> 11;                       // block-uniform (256 | 2048)
  float rn[7];
#pragma unroll
  for (int t = 0; t < 7; ++t) rn[t] = recs[(size_t)(7 + t) * NG + g];
  float term = recs[(size_t)14 * NG + g] - recs[(size_t)16 * NG + g];
  float dot = 0.f;
  if (c == 0) {
    float e0[7], st[7];
#pragma unroll
    for (int t = 0; t < 7; ++t) { e0[t] = em[(size_t)b * TT + t]; st[t] = start_t[t]; }
#pragma unroll
    for (int t = 0; t < 7; ++t) dot = fmaf(__expf(st[t] + e0[t]), rn[t], dot);
    int tg0 = tags[b];
    float em0t = e0[0], stt = st[0];
#pragma unroll
    for (int t = 1; t < 7; ++t) {
      em0t = (tg0 == t) ? e0[t] : em0t;
      stt  = (tg0 == t) ? st[t] : stt;
    }
    term += stt + em0t;                  // gold start + em[0][tag0]
  } else {
#pragma unroll
    for (int t = 0; t < 7; ++t)
      dot = fmaf(recs[(size_t)t * NG + (g - BB)], rn[t], dot);
  }
  term -= logf(dot);
  if (c == KCH - 1) {
    float fz = 0.f;
#pragma unroll
    for (int t = 0; t < 7; ++t)
      fz = fmaf(recs[(size_t)t * NG + g], __expf(end_t[t]), fz);
    term -= logf(fz);                    // final logZ term (own vn)
    float mcf = 0.f;
    for (int cc = 0; cc < KCH; ++cc)
      mcf += recs[(size_t)15 * NG + (size_t)cc * BB + b];
    int se = (int)mcf - 1;
    int te = tags[(size_t)se * BB + b];
    term += end_t[te];                   // gold end transition
  }
  __shared__ float red[256];
  red[tid] = term;
  __syncthreads();
  for (int off = 128; off > 0; off >>= 1) {
    if (tid < off) red[tid] += red[tid + off];
    __syncthreads();
  }
  if (tid == 0) partials[blockIdx.x] = red[0];
}

// ---------------------------------------------------------------------------
// Kernel 3: deterministic tree-reduce of the block partials.
// ---------------------------------------------------------------------------
__global__ __launch_bounds__(1024)
void crf_reduce_kernel(const float* __restrict__ partials, int n,
                       float* __restrict__ out) {
  __shared__ float s[1024];
  int t = threadIdx.x;
  float v = 0.f;
  for (int i = t; i < n; i += 1024) v += partials[i];
  s[t] = v;
  __syncthreads();
  for (int off = 512; off > 0; off >>= 1) {
    if (t < off) s[t] += s[t + off];
    __syncthreads();
  }
  if (t == 0) out[0] = s[0];
}

extern "C" void kernel_launch(void* const* d_in, const int* in_sizes, int n_in,
                              void* d_out, int out_size, void* d_ws, size_t ws_size,
                              hipStream_t stream) {
  const float* em      = (const float*)d_in[0];
  const int*   tags    = (const int*)d_in[1];
  const int*   qmask   = (const int*)d_in[2];
  const int*   mask    = (const int*)d_in[3];
  const float* start_t = (const float*)d_in[4];
  const float* end_t   = (const float*)d_in[5];
  const float* self_t  = (const float*)d_in[6];
  const float* other_t = (const float*)d_in[7];

  float* recs = (float*)d_ws;

  auto need = [](int kch) {
    size_t ng = (size_t)kch * BB;
    return (NFLD * ng + ng / 256) * sizeof(float);
  };

  if (ws_size >= need(128)) {
    constexpr int KCH = 128;
    constexpr int NG = KCH * BB;
    float* partials = recs + (size_t)NFLD * NG;
    crf_chunk_kernel<KCH><<<NG / 128, 256, 0, stream>>>(
        em, tags, qmask, mask, self_t, other_t, recs);
    crf_junction_kernel<KCH><<<NG / 256, 256, 0, stream>>>(
        recs, em, tags, start_t, end_t, partials);
    crf_reduce_kernel<<<1, 1024, 0, stream>>>(partials, NG / 256, (float*)d_out);
  } else {
    constexpr int KCH = 64;
    constexpr int NG = KCH * BB;
    float* partials = recs + (size_t)NFLD * NG;
    crf_chunk_kernel<KCH><<<NG / 128, 256, 0, stream>>>(
        em, tags, qmask, mask, self_t, other_t, recs);
    crf_junction_kernel<KCH><<<NG / 256, 256, 0, stream>>>(
        recs, em, tags, start_t, end_t, partials);
    crf_reduce_kernel<<<1, 1024, 0, stream>>>(partials, NG / 256, (float*)d_out);
  }
}

// Round 15
// 52.658 us; speedup vs baseline: 1.2620x; 1.2620x over previous
//
#include <hip/hip_runtime.h>
#include <hip/hip_bf16.h>

#define LSEQ 2048
#define BB   2048
#define TT   7
#define NFLD 17   // SoA fields: [0..6] vn, [7..13] rn, [14] sc, [15] mc, [16] Lmass

typedef float f4 __attribute__((ext_vector_type(4)));

// Load 7 floats from a 4B-aligned row as two overlapping dwordx4 loads.
__device__ __forceinline__ void ld7(const float* __restrict__ p, float* e) {
  f4 lo, hi;
  __builtin_memcpy(&lo, p, 16);
  __builtin_memcpy(&hi, p + 3, 16);
  e[0] = lo.x; e[1] = lo.y; e[2] = lo.z; e[3] = lo.w;
  e[4] = hi.y; e[5] = hi.z; e[6] = hi.w;
}

// ---------------------------------------------------------------------------
// Rank-1 chunk decomposition, v4. P_c = u s v^T, s = 1^T P 1.
//   forward (CC steps): w^T = 1^T P via v <- (v.E) o ee; renorm logs + final
//     sum give Lmass = log s; also gold score sc and mask count.
//   backward (NB=12 steps): u DIRECTION only. Hilbert contraction ~0.1/step
//     -> 12 steps give u to ~1e-12. Processes the chunk's FIRST 12 rows
//     (i_lo+11 down to i_lo), which forward reads concurrently -> cache-hot.
// DUAL-STREAM: each thread runs TWO independent chunks (g, g+NG/2)
// interleaved -> 2x compute between dependent loads, 2x load MLP
// (R8-R13 invariant: single-recurrence threads are latency-bound at ~83us
// regardless of occupancy; compiler collapses deeper prefetch rings).
// NOTE: no asm-load rings (R14: loop-carried asm outputs get phi-copied
// before the load lands -> garbage -> OOB index -> GPU fault).
// NOTE: no min-wave launch_bounds (R5/R7: forcing it spills to scratch).
// ---------------------------------------------------------------------------
template<int KCH>
__global__ __launch_bounds__(256)
void crf_chunk_kernel(const float* __restrict__ em,
                      const int*   __restrict__ tags,
                      const int*   __restrict__ qmask,
                      const int*   __restrict__ mask,
                      const float* __restrict__ self_t,
                      const float* __restrict__ other_t,
                      float* __restrict__ recs) {
  constexpr int CC  = LSEQ / KCH;
  constexpr int NG  = KCH * BB;
  constexpr int NGH = NG / 2;
  constexpr int NB  = 12;         // backward steps for the u direction
  __shared__ float sE[2][49];     // exp(transitions): [0]=self, [1]=other
  __shared__ float sT[2][49];     // raw transitions (gold-path score)
  int tid = threadIdx.x;
  if (tid < 49) {
    float sv = self_t[tid], ov = other_t[tid];
    sE[0][tid] = __expf(sv); sE[1][tid] = __expf(ov);
    sT[0][tid] = sv;         sT[1][tid] = ov;
  }
  __syncthreads();

  int role = tid >> 7;            // wave-uniform: 0 = forward, 1 = backward
  int p = blockIdx.x * 128 + (tid & 127);   // pair id
  int b  = p & (BB - 1);
  int c1 = p >> 11;               // uniform per block (128 | 2048)
  int c2 = c1 + KCH / 2;
  int g1 = p, g2 = p + NGH;

  float Es[49];                   // SGPR-resident via readfirstlane when uniform
  int loadedCont = -1;
  auto loadEs = [&](int cf) {
#pragma unroll
    for (int k = 0; k < 49; ++k)
      Es[k] = __int_as_float(
          __builtin_amdgcn_readfirstlane(__float_as_int(sE[cf][k])));
    loadedCont = cf;
  };

  if (role == 0) {
    // ---------------- forward: vn, Lmass, gold score (2 streams) ----------
    float vA[7], vB[7];
#pragma unroll
    for (int t = 0; t < 7; ++t) { vA[t] = 1.f; vB[t] = 1.f; }
    float scA = 0.f, scB = 0.f, LvA = 0.f, LvB = 0.f;
    int mcA = 0, mcB = 0, tpA, qpA, tpB, qpB;
    int iA = c1 * CC, iB = c2 * CC;
    if (c1 == 0) { mcA = mask[b]; tpA = tags[b]; qpA = qmask[b]; }
    else { size_t pb = (size_t)(iA - 1) * BB + b; tpA = tags[pb]; qpA = qmask[pb]; }
    { size_t pb = (size_t)(iB - 1) * BB + b; tpB = tags[pb]; qpB = qmask[pb]; }

    auto LDA = [&](int s, float* e, int& tg, int& qm, int& mi) {
      size_t base = (size_t)(iA + s) * BB + b;
      ld7(em + base * TT, e);
      tg = tags[base]; qm = qmask[base]; mi = mask[base];
    };
    auto LDB = [&](int s, float* e, int& tg, int& qm, int& mi) {
      size_t base = (size_t)(iB + s) * BB + b;
      ld7(em + base * TT, e);
      tg = tags[base]; qm = qmask[base]; mi = mask[base];
    };

    auto STEP = [&](const float* e, int tg, int qm, int mi,
                    float* v, float& sc, int& mc, int& tp, int& qp) {
      int cont = (qm != qp) ? 1 : 0;
      int cf = __builtin_amdgcn_readfirstlane(cont);
      bool uni = __all(cont == cf);
      float ee[7];
#pragma unroll
      for (int t = 0; t < 7; ++t) ee[t] = __expf(e[t]);
      float etag = e[0];
#pragma unroll
      for (int t = 1; t < 7; ++t) etag = (tg == t) ? e[t] : etag;
      float ttag = sT[cont][tp * 7 + tg];
      if (mi) { sc += ttag + etag; ++mc; }
      tp = tg; qp = qm;
      float a[7] = {0.f,0.f,0.f,0.f,0.f,0.f,0.f};
      if (uni) {
        if (cf != loadedCont) loadEs(cf);
#pragma unroll
        for (int r = 0; r < 7; ++r) {
          float vr = v[r];
#pragma unroll
          for (int t = 0; t < 7; ++t) a[t] = fmaf(vr, Es[r*7+t], a[t]);
        }
      } else {
        loadedCont = -1;
#pragma unroll
        for (int r = 0; r < 7; ++r) {
          float vr = v[r];
#pragma unroll
          for (int t = 0; t < 7; ++t) a[t] = fmaf(vr, sE[cont][r*7+t], a[t]);
        }
      }
#pragma unroll
      for (int t = 0; t < 7; ++t) v[t] = mi ? a[t] * ee[t] : v[t];
    };

    float eA0[7], eA1[7], eB0[7], eB1[7];
    int tgA0, qmA0, miA0, tgA1, qmA1, miA1;
    int tgB0, qmB0, miB0, tgB1, qmB1, miB1;
    LDA(0, eA0, tgA0, qmA0, miA0);
    LDB(0, eB0, tgB0, qmB0, miB0);

    for (int j = 0; j < CC; ++j) {
      bool more = (j + 1 < CC);                     // wave-uniform
      if (more) {
        LDA(j + 1, eA1, tgA1, qmA1, miA1);          // issue next-step loads
        LDB(j + 1, eB1, tgB1, qmB1, miB1);
      }
      int miA = (c1 == 0 && j == 0) ? 0 : miA0;     // boundary step = identity
      STEP(eA0, tgA0, qmA0, miA, vA, scA, mcA, tpA, qpA);
      STEP(eB0, tgB0, qmB0, miB0, vB, scB, mcB, tpB, qpB);
      if ((j & 7) == 7) {                           // renorm, track log mass
        float sA = vA[0]+vA[1]+vA[2]+vA[3]+vA[4]+vA[5]+vA[6];
        float sB = vB[0]+vB[1]+vB[2]+vB[3]+vB[4]+vB[5]+vB[6];
        LvA += logf(sA); LvB += logf(sB);
        float iA2 = 1.0f / sA, iB2 = 1.0f / sB;
#pragma unroll
        for (int t = 0; t < 7; ++t) { vA[t] *= iA2; vB[t] *= iB2; }
      }
      if (more) {
#pragma unroll
        for (int t = 0; t < 7; ++t) { eA0[t] = eA1[t]; eB0[t] = eB1[t]; }
        tgA0 = tgA1; qmA0 = qmA1; miA0 = miA1;
        tgB0 = tgB1; qmB0 = qmB1; miB0 = miB1;
      }
    }
    float sA = vA[0]+vA[1]+vA[2]+vA[3]+vA[4]+vA[5]+vA[6];
    float sB = vB[0]+vB[1]+vB[2]+vB[3]+vB[4]+vB[5]+vB[6];
    float iA2 = 1.0f / sA, iB2 = 1.0f / sB;
#pragma unroll
    for (int t = 0; t < 7; ++t) {
      recs[(size_t)t * NG + g1] = vA[t] * iA2;
      recs[(size_t)t * NG + g2] = vB[t] * iB2;
    }
    recs[(size_t)14 * NG + g1] = scA;
    recs[(size_t)14 * NG + g2] = scB;
    recs[(size_t)15 * NG + g1] = (float)mcA;
    recs[(size_t)15 * NG + g2] = (float)mcB;
    recs[(size_t)16 * NG + g1] = LvA + logf(sA);    // Lmass = log(1^T P 1)
    recs[(size_t)16 * NG + g2] = LvB + logf(sB);
  } else {
    // ---------------- backward: u direction, NB steps (2 streams) ---------
    float rA[7], rB[7];
#pragma unroll
    for (int t = 0; t < 7; ++t) { rA[t] = 1.f; rB[t] = 1.f; }
    int iloA = (c1 == 0) ? 1 : c1 * CC;
    int iloB = c2 * CC;

    auto LDbA = [&](int s, float* e, int& q, int& q1, int& mi) {
      size_t base = (size_t)(iloA + NB - 1 - s) * BB + b;   // i >= iloA >= 1
      ld7(em + base * TT, e);
      q = qmask[base]; q1 = qmask[base - BB]; mi = mask[base];
    };
    auto LDbB = [&](int s, float* e, int& q, int& q1, int& mi) {
      size_t base = (size_t)(iloB + NB - 1 - s) * BB + b;
      ld7(em + base * TT, e);
      q = qmask[base]; q1 = qmask[base - BB]; mi = mask[base];
    };

    auto STEPB = [&](const float* e, int q, int q1, int mi, float* r) {
      int cont = (q != q1) ? 1 : 0;
      int cf = __builtin_amdgcn_readfirstlane(cont);
      bool uni = __all(cont == cf);
      float ee[7];
#pragma unroll
      for (int t = 0; t < 7; ++t) ee[t] = __expf(e[t]);
      float tmp[7];
#pragma unroll
      for (int t = 0; t < 7; ++t) tmp[t] = ee[t] * r[t];
      float a[7] = {0.f,0.f,0.f,0.f,0.f,0.f,0.f};
      if (uni) {
        if (cf != loadedCont) loadEs(cf);
#pragma unroll
        for (int t = 0; t < 7; ++t) {
          float tt = tmp[t];
#pragma unroll
          for (int s2 = 0; s2 < 7; ++s2) a[s2] = fmaf(tt, Es[s2*7+t], a[s2]);
        }
      } else {
        loadedCont = -1;
#pragma unroll
        for (int t = 0; t < 7; ++t) {
          float tt = tmp[t];
#pragma unroll
          for (int s2 = 0; s2 < 7; ++s2) a[s2] = fmaf(tt, sE[cont][s2*7+t], a[s2]);
        }
      }
#pragma unroll
      for (int s2 = 0; s2 < 7; ++s2) r[s2] = mi ? a[s2] : r[s2];
    };

    float eA0[7], eA1[7], eB0[7], eB1[7];
    int qA0, q1A0, mA0, qA1, q1A1, mA1;
    int qB0, q1B0, mB0, qB1, q1B1, mB1;
    LDbA(0, eA0, qA0, q1A0, mA0);
    LDbB(0, eB0, qB0, q1B0, mB0);

    for (int j = 0; j < NB; ++j) {
      bool more = (j + 1 < NB);
      if (more) {
        LDbA(j + 1, eA1, qA1, q1A1, mA1);
        LDbB(j + 1, eB1, qB1, q1B1, mB1);
      }
      STEPB(eA0, qA0, q1A0, mA0, rA);
      STEPB(eB0, qB0, q1B0, mB0, rB);
      if (j == 5) {                                 // overflow guard
        float sA = rA[0]+rA[1]+rA[2]+rA[3]+rA[4]+rA[5]+rA[6];
        float sB = rB[0]+rB[1]+rB[2]+rB[3]+rB[4]+rB[5]+rB[6];
        float iA2 = 1.0f / sA, iB2 = 1.0f / sB;
#pragma unroll
        for (int t = 0; t < 7; ++t) { rA[t] *= iA2; rB[t] *= iB2; }
      }
      if (more) {
#pragma unroll
        for (int t = 0; t < 7; ++t) { eA0[t] = eA1[t]; eB0[t] = eB1[t]; }
        qA0 = qA1; q1A0 = q1A1; mA0 = mA1;
        qB0 = qB1; q1B0 = q1B1; mB0 = mB1;
      }
    }
    float sA = rA[0]+rA[1]+rA[2]+rA[3]+rA[4]+rA[5]+rA[6];
    float sB = rB[0]+rB[1]+rB[2]+rB[3]+rB[4]+rB[5]+rB[6];
    float iA2 = 1.0f / sA, iB2 = 1.0f / sB;
#pragma unroll
    for (int t = 0; t < 7; ++t) {
      recs[(size_t)(7 + t) * NG + g1] = rA[t] * iA2;
      recs[(size_t)(7 + t) * NG + g2] = rB[t] * iB2;
    }
  }
}

// ---------------------------------------------------------------------------
// Kernel 2: flat-parallel junction terms + per-block tree reduction.
// term(b,c) = sc - Lmass - log(dot); dot_0 = alpha0.rn_0 (+gold start terms),
// dot_c = vn_{c-1}.rn_c; c==KCH-1 folds the final logZ term and gold end.
// ---------------------------------------------------------------------------
template<int KCH>
__global__ __launch_bounds__(256)
void crf_junction_kernel(const float* __restrict__ recs,
                         const float* __restrict__ em,
                         const int*   __restrict__ tags,
                         const float* __restrict__ start_t,
                         const float* __restrict__ end_t,
                         float* __restrict__ partials) {
  constexpr int NG = KCH * BB;
  int tid = threadIdx.x;
  int g = blockIdx.x * 256 + tid;
  int b = g & (BB - 1);
  int c = g >> 11;                       // block-uniform (256 | 2048)
  float rn[7];
#pragma unroll
  for (int t = 0; t < 7; ++t) rn[t] = recs[(size_t)(7 + t) * NG + g];
  float term = recs[(size_t)14 * NG + g] - recs[(size_t)16 * NG + g];
  float dot = 0.f;
  if (c == 0) {
    float e0[7], st[7];
#pragma unroll
    for (int t = 0; t < 7; ++t) { e0[t] = em[(size_t)b * TT + t]; st[t] = start_t[t]; }
#pragma unroll
    for (int t = 0; t < 7; ++t) dot = fmaf(__expf(st[t] + e0[t]), rn[t], dot);
    int tg0 = tags[b];
    float em0t = e0[0], stt = st[0];
#pragma unroll
    for (int t = 1; t < 7; ++t) {
      em0t = (tg0 == t) ? e0[t] : em0t;
      stt  = (tg0 == t) ? st[t] : stt;
    }
    term += stt + em0t;                  // gold start + em[0][tag0]
  } else {
#pragma unroll
    for (int t = 0; t < 7; ++t)
      dot = fmaf(recs[(size_t)t * NG + (g - BB)], rn[t], dot);
  }
  term -= logf(dot);
  if (c == KCH - 1) {
    float fz = 0.f;
#pragma unroll
    for (int t = 0; t < 7; ++t)
      fz = fmaf(recs[(size_t)t * NG + g], __expf(end_t[t]), fz);
    term -= logf(fz);                    // final logZ term (own vn)
    float mcf = 0.f;
    for (int cc = 0; cc < KCH; ++cc)
      mcf += recs[(size_t)15 * NG + (size_t)cc * BB + b];
    int se = (int)mcf - 1;
    int te = tags[(size_t)se * BB + b];
    term += end_t[te];                   // gold end transition
  }
  __shared__ float red[256];
  red[tid] = term;
  __syncthreads();
  for (int off = 128; off > 0; off >>= 1) {
    if (tid < off) red[tid] += red[tid + off];
    __syncthreads();
  }
  if (tid == 0) partials[blockIdx.x] = red[0];
}

// ---------------------------------------------------------------------------
// Kernel 3: deterministic tree-reduce of the block partials.
// ---------------------------------------------------------------------------
__global__ __launch_bounds__(1024)
void crf_reduce_kernel(const float* __restrict__ partials, int n,
                       float* __restrict__ out) {
  __shared__ float s[1024];
  int t = threadIdx.x;
  float v = 0.f;
  for (int i = t; i < n; i += 1024) v += partials[i];
  s[t] = v;
  __syncthreads();
  for (int off = 512; off > 0; off >>= 1) {
    if (t < off) s[t] += s[t + off];
    __syncthreads();
  }
  if (t == 0) out[0] = s[0];
}

extern "C" void kernel_launch(void* const* d_in, const int* in_sizes, int n_in,
                              void* d_out, int out_size, void* d_ws, size_t ws_size,
                              hipStream_t stream) {
  const float* em      = (const float*)d_in[0];
  const int*   tags    = (const int*)d_in[1];
  const int*   qmask   = (const int*)d_in[2];
  const int*   mask    = (const int*)d_in[3];
  const float* start_t = (const float*)d_in[4];
  const float* end_t   = (const float*)d_in[5];
  const float* self_t  = (const float*)d_in[6];
  const float* other_t = (const float*)d_in[7];

  float* recs = (float*)d_ws;

  constexpr int KCH = 64;     // CC=32; ws need ~8.9 MB
  constexpr int NG  = KCH * BB;
  float* partials = recs + (size_t)NFLD * NG;

  crf_chunk_kernel<KCH><<<(NG / 2) / 128, 256, 0, stream>>>(
      em, tags, qmask, mask, self_t, other_t, recs);
  crf_junction_kernel<KCH><<<NG / 256, 256, 0, stream>>>(
      recs, em, tags, start_t, end_t, partials);
  crf_reduce_kernel<<<1, 1024, 0, stream>>>(partials, NG / 256, (float*)d_out);
}